// Round 3
// baseline (175.202 us; speedup 1.0000x reference)
//
#include <hip/hip_runtime.h>

#define CDIM 512
#define OKD  256
#define NDIM 4096
#define NT   32

// ws float offsets
#define OFF_XMH 0          // B*C*64 = 131072
#define OFF_X1  131072     // B*C*16 = 32768
#define OFF_K1  163840     // B*256*16 = 16384
#define OFF_M1  180224     // B*C*16 = 32768
#define OFF_CB1 212992     // 64
#define OFF_VM  213056     // B*C*64 = 131072

// ---------------------------------------------------------------------------
// K1: x -> xmh[b,c,64] (h-mean) and x1pe[b,c,16] (h-mean + 4w-mean + pe)
__global__ __launch_bounds__(256) void k_reduce(const float* __restrict__ x,
                                                const float* __restrict__ pe,
                                                const int* __restrict__ pos,
                                                float* __restrict__ xmh,
                                                float* __restrict__ x1pe) {
  int t = threadIdx.x;
  int bc = blockIdx.x * 4 + (t >> 6);   // B*C = 2048, grid 512
  int w4 = t & 15;
  int hoff = (t >> 4) & 3;
  const float4* xp = (const float4*)(x) + (size_t)bc * (64 * 16);
  float4 acc = make_float4(0.f, 0.f, 0.f, 0.f);
#pragma unroll
  for (int k = 0; k < 16; ++k) {
    float4 v = xp[(hoff + 4 * k) * 16 + w4];
    acc.x += v.x; acc.y += v.y; acc.z += v.z; acc.w += v.w;
  }
  acc.x += __shfl_xor(acc.x, 16); acc.y += __shfl_xor(acc.y, 16);
  acc.z += __shfl_xor(acc.z, 16); acc.w += __shfl_xor(acc.w, 16);
  acc.x += __shfl_xor(acc.x, 32); acc.y += __shfl_xor(acc.y, 32);
  acc.z += __shfl_xor(acc.z, 32); acc.w += __shfl_xor(acc.w, 32);
  if (hoff == 0) {
    const float inv = 1.f / 64.f;
    float4 o = make_float4(acc.x * inv, acc.y * inv, acc.z * inv, acc.w * inv);
    ((float4*)xmh)[bc * 16 + w4] = o;
    int b = bc >> 9;
    int c = bc & 511;
    int ps = pos[b * 4096 + 4 * w4] >> 3;          // pos[b,0,4*i] // 8
    float x1 = (o.x + o.y + o.z + o.w) * 0.25f + pe[ps * CDIM + c];
    x1pe[bc * 16 + w4] = x1;
  }
}

// ---------------------------------------------------------------------------
// K2: vm[b,c,w] = Wv@xmh + bv  (blocks 0..127)
//     K1[b,o,i] = Wk@x1pe + bk (blocks 128..191)
__global__ __launch_bounds__(256) void k_vmk1(const float* __restrict__ Wv,
                                              const float* __restrict__ bv,
                                              const float* __restrict__ Wk,
                                              const float* __restrict__ bk,
                                              const float* __restrict__ xmh,
                                              const float* __restrict__ x1pe,
                                              float* __restrict__ vm,
                                              float* __restrict__ K1) {
  __shared__ float xsh[64][68];
  int t = threadIdx.x;
  int blk = blockIdx.x;
  if (blk < 128) {
    int b = blk >> 5;
    int c0 = (blk & 31) * 16;
    int c = c0 + (t >> 4);
    int wq = t & 15;
    const float* Wr = Wv + c * CDIM;
    float a0 = 0.f, a1 = 0.f, a2 = 0.f, a3 = 0.f;
    int cpl = t >> 2, quad = t & 3;
    for (int cp0 = 0; cp0 < CDIM; cp0 += 64) {
      __syncthreads();
#pragma unroll
      for (int rr = 0; rr < 4; ++rr) {
        *(float4*)&xsh[cpl][quad * 16 + rr * 4] =
            *(const float4*)&xmh[((size_t)(b * CDIM + cp0 + cpl)) * 64 + quad * 16 + rr * 4];
      }
      __syncthreads();
#pragma unroll 8
      for (int cp = 0; cp < 64; ++cp) {
        float wv = Wr[cp0 + cp];
        float4 xv = *(const float4*)&xsh[cp][wq * 4];
        a0 += wv * xv.x; a1 += wv * xv.y; a2 += wv * xv.z; a3 += wv * xv.w;
      }
    }
    float bb = bv[c];
    float4 o = make_float4(a0 + bb, a1 + bb, a2 + bb, a3 + bb);
    *(float4*)&vm[((size_t)(b * CDIM + c)) * 64 + wq * 4] = o;
  } else {
    int idx = blk - 128;                 // 0..63
    int b = idx >> 4;
    int o = (idx & 15) * 16 + (t >> 4);
    int i = t & 15;
    const float* Wr = Wk + o * CDIM;
    const float* xb = x1pe + (b << 9) * 16 + i;
    float acc = bk[o];
#pragma unroll 8
    for (int c = 0; c < CDIM; ++c) acc += Wr[c] * xb[c * 16];
    K1[((b << 8) + o) * 16 + i] = acc;
  }
}

// ---------------------------------------------------------------------------
// K3: M1[b,c,i] = Wq^T @ K1 (blocks 0..127) ; cb1[b,i] = bq . K1 (block 128)
__global__ __launch_bounds__(256) void k_m1(const float* __restrict__ Wq,
                                            const float* __restrict__ bq,
                                            const float* __restrict__ K1,
                                            float* __restrict__ M1,
                                            float* __restrict__ cb1) {
  int t = threadIdx.x;
  int blk = blockIdx.x;
  if (blk < 128) {
    int b = blk >> 5;
    int c = (blk & 31) * 16 + (t >> 4);
    int i = t & 15;
    const float* Wc = Wq + c;
    const float* Kb = K1 + (b << 8) * 16 + i;
    float acc = 0.f;
#pragma unroll 8
    for (int o = 0; o < OKD; ++o) acc += Wc[o * CDIM] * Kb[o * 16];
    M1[((b << 9) + c) * 16 + i] = acc;
  } else if (t < 64) {
    int b = t >> 4, i = t & 15;
    const float* Kb = K1 + (b << 8) * 16 + i;
    float acc = 0.f;
    for (int o = 0; o < OKD; ++o) acc += bq[o] * Kb[o * 16];
    cb1[b * 16 + i] = acc;
  }
}

// ---------------------------------------------------------------------------
// K4: fused attention per (b, 32-row n-tile).
// LDS layout (44160 B total):
//   [0,      9216)  es[64][36]   p[w][n]          (persistent)
//   [9216,  43008)  phase C: vs[64][132] vm chunk [w][c]
//   [9216,  41984)  phase A: m1f[8192]   M1[b] (c-major, [c][i])
//   [41984, 44160)  phase A/B: e1s[32][17]
__global__ __launch_bounds__(256) void k_attn(const float* __restrict__ x,
                                              const float* __restrict__ M1,
                                              const float* __restrict__ cb1,
                                              const float* __restrict__ vm,
                                              const float* __restrict__ gamma,
                                              float* __restrict__ out) {
  __shared__ __align__(16) char smem[44160];
  float (*es)[36]  = (float (*)[36])smem;
  float*  m1f      = (float*)(smem + 9216);
  float (*e1s)[17] = (float (*)[17])(smem + 9216 + 32768);
  float (*vs)[132] = (float (*)[132])(smem + 9216);

  int t = threadIdx.x;
  int b = blockIdx.x >> 7;
  int n0 = (blockIdx.x & 127) * NT;

  // ---- stage M1[b] (8192 floats) into LDS, coalesced ----------------------
  {
    const float4* src = (const float4*)(M1 + (b << 13));
    float4* dst = (float4*)m1f;
#pragma unroll
    for (int k = 0; k < 8; ++k) dst[t + k * 256] = src[t + k * 256];
  }
  __syncthreads();

  // ---- Phase A: E1[n][2i] per thread, barrier-free c-loop -----------------
  {
    int an = t & 31;
    int ig = t >> 5;                 // i = 2*ig, 2*ig+1
    const float* xcol = x + (size_t)(b * CDIM) * NDIM + n0 + an;
    float a0 = 0.f, a1 = 0.f, a2 = 0.f, a3 = 0.f;
#pragma unroll 4
    for (int c = 0; c < CDIM; c += 2) {
      float x0 = xcol[(size_t)c * NDIM];
      float x1 = xcol[(size_t)(c + 1) * NDIM];
      float2 m0 = *(const float2*)&m1f[(c << 4) + 2 * ig];
      float2 m1v = *(const float2*)&m1f[((c + 1) << 4) + 2 * ig];
      a0 += x0 * m0.x;  a1 += x0 * m0.y;
      a2 += x1 * m1v.x; a3 += x1 * m1v.y;
    }
    float cb0 = cb1[b * 16 + 2 * ig];
    float cb1v = cb1[b * 16 + 2 * ig + 1];
    e1s[an][2 * ig]     = a0 + a2 + cb0;
    e1s[an][2 * ig + 1] = a1 + a3 + cb1v;
  }
  __syncthreads();

  // ---- Phase B: interp to w=64 + softmax over w ---------------------------
  {
    int sn = t >> 3;    // 0..31
    int wg = t & 7;     // 8 w's per thread
    float pv[8];
    float m = -3.4e38f;
#pragma unroll
    for (int j = 0; j < 8; ++j) {
      int w = wg * 8 + j;
      float src = (float)w * (15.0f / 63.0f);
      int i0 = (int)src;
      float tf = src - (float)i0;
      int i1 = i0 + 1; if (i1 > 15) i1 = 15;
      float ev = e1s[sn][i0] * (1.0f - tf) + e1s[sn][i1] * tf;
      pv[j] = ev;
      m = fmaxf(m, ev);
    }
    m = fmaxf(m, __shfl_xor(m, 1));
    m = fmaxf(m, __shfl_xor(m, 2));
    m = fmaxf(m, __shfl_xor(m, 4));
    float s = 0.f;
#pragma unroll
    for (int j = 0; j < 8; ++j) { pv[j] = __expf(pv[j] - m); s += pv[j]; }
    s += __shfl_xor(s, 1);
    s += __shfl_xor(s, 2);
    s += __shfl_xor(s, 4);
    float inv = 1.f / s;
#pragma unroll
    for (int j = 0; j < 8; ++j) es[wg * 8 + j][sn] = pv[j] * inv;
  }

  // ---- Phase C: out = gamma * vm @ p^T + x --------------------------------
  int cg = t >> 3;     // 0..31 -> 4 c each
  int ng = t & 7;      // -> 4 n each
  float g = gamma[0];
  for (int cc0 = 0; cc0 < CDIM; cc0 += 128) {
    __syncthreads();
    {
      int cl = t >> 1, half = t & 1;
      const float* vr = vm + (size_t)(b * CDIM + cc0 + cl) * 64 + half * 32;
#pragma unroll
      for (int j = 0; j < 8; ++j) {
        float4 v = *(const float4*)&vr[j * 4];
        int w = half * 32 + j * 4;
        vs[w][cl] = v.x; vs[w + 1][cl] = v.y; vs[w + 2][cl] = v.z; vs[w + 3][cl] = v.w;
      }
    }
    __syncthreads();
    float acc[4][4] = {};
#pragma unroll 8
    for (int w = 0; w < 64; ++w) {
      float4 vv = *(const float4*)&vs[w][cg * 4];
      float4 pp = *(const float4*)&es[w][ng * 4];
      acc[0][0] += vv.x * pp.x; acc[0][1] += vv.x * pp.y; acc[0][2] += vv.x * pp.z; acc[0][3] += vv.x * pp.w;
      acc[1][0] += vv.y * pp.x; acc[1][1] += vv.y * pp.y; acc[1][2] += vv.y * pp.z; acc[1][3] += vv.y * pp.w;
      acc[2][0] += vv.z * pp.x; acc[2][1] += vv.z * pp.y; acc[2][2] += vv.z * pp.z; acc[2][3] += vv.z * pp.w;
      acc[3][0] += vv.w * pp.x; acc[3][1] += vv.w * pp.y; acc[3][2] += vv.w * pp.z; acc[3][3] += vv.w * pp.w;
    }
#pragma unroll
    for (int j = 0; j < 4; ++j) {
      int c = cc0 + cg * 4 + j;
      size_t base = (size_t)(b * CDIM + c) * NDIM + n0 + ng * 4;
      float4 xr = *(const float4*)&x[base];
      float4 o;
      o.x = g * acc[j][0] + xr.x;
      o.y = g * acc[j][1] + xr.y;
      o.z = g * acc[j][2] + xr.z;
      o.w = g * acc[j][3] + xr.w;
      *(float4*)&out[base] = o;
    }
  }
}

// ---------------------------------------------------------------------------
extern "C" void kernel_launch(void* const* d_in, const int* in_sizes, int n_in,
                              void* d_out, int out_size, void* d_ws, size_t ws_size,
                              hipStream_t stream) {
  const float* x     = (const float*)d_in[0];
  const float* Wq    = (const float*)d_in[1];
  const float* bq    = (const float*)d_in[2];
  const float* Wk    = (const float*)d_in[3];
  const float* bk    = (const float*)d_in[4];
  const float* Wv    = (const float*)d_in[5];
  const float* bv    = (const float*)d_in[6];
  const float* gamma = (const float*)d_in[7];
  const float* pe    = (const float*)d_in[8];
  const int*   pos   = (const int*)d_in[9];
  float* out = (float*)d_out;
  float* ws  = (float*)d_ws;

  float* xmh  = ws + OFF_XMH;
  float* x1pe = ws + OFF_X1;
  float* K1   = ws + OFF_K1;
  float* M1   = ws + OFF_M1;
  float* cb1  = ws + OFF_CB1;
  float* vm   = ws + OFF_VM;

  hipLaunchKernelGGL(k_reduce, dim3(512), dim3(256), 0, stream, x, pe, pos, xmh, x1pe);
  hipLaunchKernelGGL(k_vmk1, dim3(192), dim3(256), 0, stream, Wv, bv, Wk, bk, xmh, x1pe, vm, K1);
  hipLaunchKernelGGL(k_m1, dim3(129), dim3(256), 0, stream, Wq, bq, K1, M1, cb1);
  hipLaunchKernelGGL(k_attn, dim3(512), dim3(256), 0, stream, x, M1, cb1, vm, gamma, out);
}

// Round 4
// 149.069 us; speedup vs baseline: 1.1753x; 1.1753x over previous
//
#include <hip/hip_runtime.h>

#define CDIM 512
#define OKD  256
#define NDIM 4096
#define NT   32

// ws float offsets
#define OFF_XMH 0          // B*C*64 = 131072
#define OFF_X1  131072     // B*C*16 = 32768
#define OFF_K1  163840     // B*256*16 = 16384
#define OFF_M1  180224     // B*C*16 = 32768
#define OFF_CB1 212992     // 64
#define OFF_VMB 213056     // bf16 vm: B*C*64 ushorts = 131072 ushort (65536 float slots)

typedef float f32x4  __attribute__((ext_vector_type(4)));
typedef short shortx4 __attribute__((ext_vector_type(4)));
typedef short shortx8 __attribute__((ext_vector_type(8)));
typedef unsigned short ushortx4 __attribute__((ext_vector_type(4)));

static __device__ __forceinline__ unsigned short f2bf(float f) {
  unsigned u = __float_as_uint(f);
  u = (u + 0x7FFFu + ((u >> 16) & 1u)) >> 16;
  return (unsigned short)u;
}

// ---------------------------------------------------------------------------
// K1: x -> xmh[b,c,64] (h-mean) and x1pe[b,c,16] (h-mean + 4w-mean + pe)
__global__ __launch_bounds__(256) void k_reduce(const float* __restrict__ x,
                                                const float* __restrict__ pe,
                                                const int* __restrict__ pos,
                                                float* __restrict__ xmh,
                                                float* __restrict__ x1pe) {
  int t = threadIdx.x;
  int bc = blockIdx.x * 4 + (t >> 6);   // B*C = 2048, grid 512
  int w4 = t & 15;
  int hoff = (t >> 4) & 3;
  const float4* xp = (const float4*)(x) + (size_t)bc * (64 * 16);
  float4 acc = make_float4(0.f, 0.f, 0.f, 0.f);
#pragma unroll
  for (int k = 0; k < 16; ++k) {
    float4 v = xp[(hoff + 4 * k) * 16 + w4];
    acc.x += v.x; acc.y += v.y; acc.z += v.z; acc.w += v.w;
  }
  acc.x += __shfl_xor(acc.x, 16); acc.y += __shfl_xor(acc.y, 16);
  acc.z += __shfl_xor(acc.z, 16); acc.w += __shfl_xor(acc.w, 16);
  acc.x += __shfl_xor(acc.x, 32); acc.y += __shfl_xor(acc.y, 32);
  acc.z += __shfl_xor(acc.z, 32); acc.w += __shfl_xor(acc.w, 32);
  if (hoff == 0) {
    const float inv = 1.f / 64.f;
    float4 o = make_float4(acc.x * inv, acc.y * inv, acc.z * inv, acc.w * inv);
    ((float4*)xmh)[bc * 16 + w4] = o;
    int b = bc >> 9;
    int c = bc & 511;
    int ps = pos[b * 4096 + 4 * w4] >> 3;          // pos[b,0,4*i] // 8
    float x1 = (o.x + o.y + o.z + o.w) * 0.25f + pe[ps * CDIM + c];
    x1pe[bc * 16 + w4] = x1;
  }
}

// ---------------------------------------------------------------------------
// K2: vmb[b,c,w] = bf16(Wv@xmh + bv)  (blocks 0..127)
//     K1[b,o,i]  = Wk@x1pe + bk        (blocks 128..191)
__global__ __launch_bounds__(256) void k_vmk1(const float* __restrict__ Wv,
                                              const float* __restrict__ bv,
                                              const float* __restrict__ Wk,
                                              const float* __restrict__ bk,
                                              const float* __restrict__ xmh,
                                              const float* __restrict__ x1pe,
                                              unsigned short* __restrict__ vmb,
                                              float* __restrict__ K1) {
  __shared__ float xsh[64][68];
  int t = threadIdx.x;
  int blk = blockIdx.x;
  if (blk < 128) {
    int b = blk >> 5;
    int c0 = (blk & 31) * 16;
    int c = c0 + (t >> 4);
    int wq = t & 15;
    const float* Wr = Wv + c * CDIM;
    float a0 = 0.f, a1 = 0.f, a2 = 0.f, a3 = 0.f;
    int cpl = t >> 2, quad = t & 3;
    for (int cp0 = 0; cp0 < CDIM; cp0 += 64) {
      __syncthreads();
#pragma unroll
      for (int rr = 0; rr < 4; ++rr) {
        *(float4*)&xsh[cpl][quad * 16 + rr * 4] =
            *(const float4*)&xmh[((size_t)(b * CDIM + cp0 + cpl)) * 64 + quad * 16 + rr * 4];
      }
      __syncthreads();
#pragma unroll 8
      for (int cp = 0; cp < 64; ++cp) {
        float wv = Wr[cp0 + cp];
        float4 xv = *(const float4*)&xsh[cp][wq * 4];
        a0 += wv * xv.x; a1 += wv * xv.y; a2 += wv * xv.z; a3 += wv * xv.w;
      }
    }
    float bb = bv[c];
    ushortx4 pu;
    pu.x = f2bf(a0 + bb); pu.y = f2bf(a1 + bb); pu.z = f2bf(a2 + bb); pu.w = f2bf(a3 + bb);
    *(ushortx4*)&vmb[((size_t)(b * CDIM + c)) * 64 + wq * 4] = pu;
  } else {
    int idx = blk - 128;                 // 0..63
    int b = idx >> 4;
    int o = (idx & 15) * 16 + (t >> 4);
    int i = t & 15;
    const float* Wr = Wk + o * CDIM;
    const float* xb = x1pe + (b << 9) * 16 + i;
    float acc = bk[o];
#pragma unroll 8
    for (int c = 0; c < CDIM; ++c) acc += Wr[c] * xb[c * 16];
    K1[((b << 8) + o) * 16 + i] = acc;
  }
}

// ---------------------------------------------------------------------------
// K3: M1[b,c,i] = Wq^T @ K1 (blocks 0..127) ; cb1[b,i] = bq . K1 (block 128)
__global__ __launch_bounds__(256) void k_m1(const float* __restrict__ Wq,
                                            const float* __restrict__ bq,
                                            const float* __restrict__ K1,
                                            float* __restrict__ M1,
                                            float* __restrict__ cb1) {
  int t = threadIdx.x;
  int blk = blockIdx.x;
  if (blk < 128) {
    int b = blk >> 5;
    int c = (blk & 31) * 16 + (t >> 4);
    int i = t & 15;
    const float* Wc = Wq + c;
    const float* Kb = K1 + (b << 8) * 16 + i;
    float acc = 0.f;
#pragma unroll 8
    for (int o = 0; o < OKD; ++o) acc += Wc[o * CDIM] * Kb[o * 16];
    M1[((b << 9) + c) * 16 + i] = acc;
  } else if (t < 64) {
    int b = t >> 4, i = t & 15;
    const float* Kb = K1 + (b << 8) * 16 + i;
    float acc = 0.f;
    for (int o = 0; o < OKD; ++o) acc += bq[o] * Kb[o * 16];
    cb1[b * 16 + i] = acc;
  }
}

// ---------------------------------------------------------------------------
// K4: fused attention per (b, 32-row n-tile), 512 threads.
//   Phase A (VALU fp32): E1[n][i] = x_tile^T @ M1        (LDS-tiled, 4n x 4i regs)
//   Phase B (regs only): lerp i->w, softmax over w via __shfl, pack bf16 -> p_t (swizzled)
//   Phase C (MFMA bf16): out = gamma * (vm @ p^T) + x
// LDS (55296 B): [0,32768) m1f fp32[512][16] | [32768,51200) xs fp32[128][36]
//                e1p fp32[16][32][20] overlays [0,40960) after phase A
//                [51200,55296) p_t bf16[32][64] XOR-swizzled (8B granules)
__global__ __launch_bounds__(512, 4) void k_attn(const float* __restrict__ x,
                                                 const float* __restrict__ M1,
                                                 const float* __restrict__ cb1,
                                                 const unsigned short* __restrict__ vmb,
                                                 const float* __restrict__ gamma,
                                                 float* __restrict__ out) {
  __shared__ __align__(16) char smem[55296];
  float* m1f = (float*)smem;                        // [512*16]
  float (*xs)[36] = (float (*)[36])(smem + 32768);  // [128][36]
  float* e1p = (float*)smem;                        // overlay, [16][32][20] flat
  char* p_t = smem + 51200;                         // bf16 [32][64] swizzled

  const int t = threadIdx.x;
  const int lane = t & 63;
  const int b = blockIdx.x >> 7;
  const int n0 = (blockIdx.x & 127) * NT;

  // ---- stage M1[b] (8192 floats) into LDS --------------------------------
  {
    const float4* src = (const float4*)(M1 + (b << 13));
    float4* dst = (float4*)m1f;
#pragma unroll
    for (int k2 = 0; k2 < 4; ++k2) dst[t + k2 * 512] = src[t + k2 * 512];
  }

  // ---- Phase A: E1 partials, 4 chunks of 128 c ---------------------------
  const int q  = t & 7;          // n-quad: n = q*4..+3
  const int ig = (t >> 3) & 3;   // i-quad: i = ig*4..+3
  const int cg = t >> 5;         // c-subgroup 0..15
  float acc[4][4] = {};
  for (int ch = 0; ch < 4; ++ch) {
    const int c0 = ch * 128;
    if (ch) __syncthreads();     // xs reuse
    {
      const int c_l = t >> 2, nq = t & 3;
      const float* gp = x + (size_t)(b * CDIM + c0 + c_l) * NDIM + n0 + nq * 8;
      float4 v0 = *(const float4*)gp;
      float4 v1 = *(const float4*)(gp + 4);
      *(float4*)&xs[c_l][nq * 8]     = v0;
      *(float4*)&xs[c_l][nq * 8 + 4] = v1;
    }
    __syncthreads();
#pragma unroll
    for (int cc = 0; cc < 8; ++cc) {
      const int c_l = cg * 8 + cc;
      float4 x4 = *(const float4*)&xs[c_l][q * 4];
      float4 m4 = *(const float4*)&m1f[(c0 + c_l) * 16 + ig * 4];
      acc[0][0] += x4.x * m4.x; acc[0][1] += x4.x * m4.y; acc[0][2] += x4.x * m4.z; acc[0][3] += x4.x * m4.w;
      acc[1][0] += x4.y * m4.x; acc[1][1] += x4.y * m4.y; acc[1][2] += x4.y * m4.z; acc[1][3] += x4.y * m4.w;
      acc[2][0] += x4.z * m4.x; acc[2][1] += x4.z * m4.y; acc[2][2] += x4.z * m4.z; acc[2][3] += x4.z * m4.w;
      acc[3][0] += x4.w * m4.x; acc[3][1] += x4.w * m4.y; acc[3][2] += x4.w * m4.z; acc[3][3] += x4.w * m4.w;
    }
  }
  __syncthreads();               // m1f/xs dead -> e1p overlay safe
#pragma unroll
  for (int jn = 0; jn < 4; ++jn) {
    float4 w4 = make_float4(acc[jn][0], acc[jn][1], acc[jn][2], acc[jn][3]);
    *(float4*)&e1p[(cg * 32 + q * 4 + jn) * 20 + ig * 4] = w4;
  }
  __syncthreads();

  // ---- Phase B: reduce partials, lerp i->w, softmax (all in regs) --------
  {
    const int sn = t >> 4;       // n 0..31
    const int si = t & 15;       // i
    float ev = cb1[b * 16 + si];
#pragma unroll
    for (int g = 0; g < 16; ++g) ev += e1p[g * 640 + sn * 20 + si];
    float pv[4];
    float mx = -3.4e38f;
#pragma unroll
    for (int j = 0; j < 4; ++j) {
      int w = si * 4 + j;
      float srcf = (float)w * (15.0f / 63.0f);
      int i0 = (int)srcf;
      float tf = srcf - (float)i0;
      int i1 = i0 + 1; if (i1 > 15) i1 = 15;
      float v0 = __shfl(ev, (lane & 48) | i0);
      float v1 = __shfl(ev, (lane & 48) | i1);
      float vv = v0 * (1.0f - tf) + v1 * tf;
      pv[j] = vv;
      mx = fmaxf(mx, vv);
    }
    mx = fmaxf(mx, __shfl_xor(mx, 1));
    mx = fmaxf(mx, __shfl_xor(mx, 2));
    mx = fmaxf(mx, __shfl_xor(mx, 4));
    mx = fmaxf(mx, __shfl_xor(mx, 8));
    float s = 0.f;
#pragma unroll
    for (int j = 0; j < 4; ++j) { pv[j] = __expf(pv[j] - mx); s += pv[j]; }
    s += __shfl_xor(s, 1); s += __shfl_xor(s, 2);
    s += __shfl_xor(s, 4); s += __shfl_xor(s, 8);
    float inv = 1.0f / s;
    ushortx4 pu;
    pu.x = f2bf(pv[0] * inv); pu.y = f2bf(pv[1] * inv);
    pu.z = f2bf(pv[2] * inv); pu.w = f2bf(pv[3] * inv);
    // XOR-swizzled 8B-granule store: row sn (128B), granule si ^ (sn&15)
    *(ushortx4*)(p_t + sn * 128 + ((si ^ (sn & 15)) << 3)) = pu;
  }
  __syncthreads();

  // ---- Phase C: MFMA PV + residual ---------------------------------------
  {
    const int wid = t >> 6;
    const float gm = gamma[0];
    const int nrel = lane & 15;
    const int kg = lane >> 4;    // 0..3
#pragma unroll
    for (int j = 0; j < 8; ++j) {
      const int idx = wid * 8 + j;
      const int ct = idx >> 1, nt = idx & 1;
      f32x4 dacc = {0.f, 0.f, 0.f, 0.f};
      const unsigned short* vrow =
          vmb + ((size_t)(b * CDIM + ct * 16 + nrel)) * 64 + kg * 4;
      const char* prow = p_t + (nt * 16 + nrel) * 128;
#pragma unroll
      for (int ks = 0; ks < 2; ++ks) {
        // A: vm[c][k], k-slots: {ks*32+4kg+0..3, ks*32+16+4kg+0..3}
        shortx4 a0 = *(const shortx4*)(vrow + ks * 32);
        shortx4 a1 = *(const shortx4*)(vrow + ks * 32 + 16);
        shortx8 av = __builtin_shufflevector(a0, a1, 0, 1, 2, 3, 4, 5, 6, 7);
        // B: p[n][k], same k-slot formula, swizzled granules
        int G0 = (ks * 8 + kg) ^ nrel;
        int G1 = (ks * 8 + 4 + kg) ^ nrel;
        shortx4 b0 = *(const shortx4*)(prow + G0 * 8);
        shortx4 b1 = *(const shortx4*)(prow + G1 * 8);
        shortx8 bv2 = __builtin_shufflevector(b0, b1, 0, 1, 2, 3, 4, 5, 6, 7);
        dacc = __builtin_amdgcn_mfma_f32_16x16x32_bf16(av, bv2, dacc, 0, 0, 0);
      }
#pragma unroll
      for (int r = 0; r < 4; ++r) {
        int c_o = ct * 16 + kg * 4 + r;   // D: row=(lane>>4)*4+reg, col=lane&15
        size_t base = (size_t)(b * CDIM + c_o) * NDIM + n0 + nt * 16 + nrel;
        out[base] = gm * dacc[r] + x[base];
      }
    }
  }
}

// ---------------------------------------------------------------------------
extern "C" void kernel_launch(void* const* d_in, const int* in_sizes, int n_in,
                              void* d_out, int out_size, void* d_ws, size_t ws_size,
                              hipStream_t stream) {
  const float* x     = (const float*)d_in[0];
  const float* Wq    = (const float*)d_in[1];
  const float* bq    = (const float*)d_in[2];
  const float* Wk    = (const float*)d_in[3];
  const float* bk    = (const float*)d_in[4];
  const float* Wv    = (const float*)d_in[5];
  const float* bv    = (const float*)d_in[6];
  const float* gamma = (const float*)d_in[7];
  const float* pe    = (const float*)d_in[8];
  const int*   pos   = (const int*)d_in[9];
  float* out = (float*)d_out;
  float* ws  = (float*)d_ws;

  float* xmh  = ws + OFF_XMH;
  float* x1pe = ws + OFF_X1;
  float* K1   = ws + OFF_K1;
  float* M1   = ws + OFF_M1;
  float* cb1  = ws + OFF_CB1;
  unsigned short* vmb = (unsigned short*)(ws + OFF_VMB);

  hipLaunchKernelGGL(k_reduce, dim3(512), dim3(256), 0, stream, x, pe, pos, xmh, x1pe);
  hipLaunchKernelGGL(k_vmk1, dim3(192), dim3(256), 0, stream, Wv, bv, Wk, bk, xmh, x1pe, vmb, K1);
  hipLaunchKernelGGL(k_m1, dim3(129), dim3(256), 0, stream, Wq, bq, K1, M1, cb1);
  hipLaunchKernelGGL(k_attn, dim3(512), dim3(512), 0, stream, x, M1, cb1, vmb, gamma, out);
}

// Round 5
// 138.038 us; speedup vs baseline: 1.2692x; 1.0799x over previous
//
#include <hip/hip_runtime.h>

#define CDIM 512
#define OKD  256
#define NDIM 4096

// ws float offsets
#define OFF_XMH 0          // fp32 B*C*64 = 131072
#define OFF_X1  131072     // fp32 B*C*16 = 32768
#define OFF_K1  163840     // fp32 B*256*16 = 16384
#define OFF_M1A 180224     // bf16 fragment-layout M1: 4b*8192 ushort = 16384 float slots
#define OFF_CB1 196608     // 64
#define OFF_VMB 196672     // bf16 vm [b][c][w]: 131072 ushort = 65536 float slots

typedef float f32x4  __attribute__((ext_vector_type(4)));
typedef short shortx4 __attribute__((ext_vector_type(4)));
typedef short shortx8 __attribute__((ext_vector_type(8)));

static __device__ __forceinline__ unsigned short f2bf(float f) {
  unsigned u = __float_as_uint(f);
  u = (u + 0x7FFFu + ((u >> 16) & 1u)) >> 16;
  return (unsigned short)u;
}
static __device__ __forceinline__ unsigned pk2(float lo, float hi) {
  return (unsigned)f2bf(lo) | ((unsigned)f2bf(hi) << 16);
}

// ---------------------------------------------------------------------------
// K1: x -> xmh[b,c,64] (h-mean, fp32) and x1pe[b,c,16] (h-mean + 4w-mean + pe)
__global__ __launch_bounds__(256) void k_reduce(const float* __restrict__ x,
                                                const float* __restrict__ pe,
                                                const int* __restrict__ pos,
                                                float* __restrict__ xmh,
                                                float* __restrict__ x1pe) {
  int t = threadIdx.x;
  int bc = blockIdx.x * 4 + (t >> 6);   // B*C = 2048, grid 512
  int w4 = t & 15;
  int hoff = (t >> 4) & 3;
  const float4* xp = (const float4*)(x) + (size_t)bc * (64 * 16);
  float4 acc = make_float4(0.f, 0.f, 0.f, 0.f);
#pragma unroll
  for (int k = 0; k < 16; ++k) {
    float4 v = xp[(hoff + 4 * k) * 16 + w4];
    acc.x += v.x; acc.y += v.y; acc.z += v.z; acc.w += v.w;
  }
  acc.x += __shfl_xor(acc.x, 16); acc.y += __shfl_xor(acc.y, 16);
  acc.z += __shfl_xor(acc.z, 16); acc.w += __shfl_xor(acc.w, 16);
  acc.x += __shfl_xor(acc.x, 32); acc.y += __shfl_xor(acc.y, 32);
  acc.z += __shfl_xor(acc.z, 32); acc.w += __shfl_xor(acc.w, 32);
  if (hoff == 0) {
    const float inv = 1.f / 64.f;
    float4 o = make_float4(acc.x * inv, acc.y * inv, acc.z * inv, acc.w * inv);
    ((float4*)xmh)[bc * 16 + w4] = o;
    int b = bc >> 9;
    int c = bc & 511;
    int ps = pos[b * 4096 + 4 * w4] >> 3;
    float x1 = (o.x + o.y + o.z + o.w) * 0.25f + pe[ps * CDIM + c];
    x1pe[bc * 16 + w4] = x1;
  }
}

// ---------------------------------------------------------------------------
// K2 (128 thr):
//  blocks 0..63:  vm MFMA: vmb[b,c,w] = bf16(Wv@xmh + bv)
//                 wave = (b, cgrp, wt): 4 c-tiles x 1 w-tile, K=512
//  blocks 64..191: K1[b,o,i] = Wk@x1pe + bk (VALU)
__global__ __launch_bounds__(128) void k_vmk1(const float* __restrict__ Wv,
                                              const float* __restrict__ bv,
                                              const float* __restrict__ Wk,
                                              const float* __restrict__ bk,
                                              const float* __restrict__ xmh,
                                              const float* __restrict__ x1pe,
                                              unsigned short* __restrict__ vmb,
                                              float* __restrict__ K1) {
  int t = threadIdx.x;
  int blk = blockIdx.x;
  if (blk < 64) {
    int wid = blk * 2 + (t >> 6);
    int lane = t & 63, nrel = lane & 15, kg = lane >> 4;
    int b = wid >> 5, rem = wid & 31, cgrp = rem >> 2, wt = rem & 3;
    f32x4 acc[4] = {{0,0,0,0},{0,0,0,0},{0,0,0,0},{0,0,0,0}};
    for (int kt = 0; kt < 16; ++kt) {
      // B-frag: xmh[b][cp][w], cp = kt*32 + kg*4 + {0..3,16..19}, w = wt*16+nrel
      const float* xp = xmh + (size_t)(b * 512 + kt * 32 + kg * 4) * 64 + wt * 16 + nrel;
      float v0 = xp[0], v1 = xp[64], v2 = xp[128], v3 = xp[192];
      float v4 = xp[1024], v5 = xp[1088], v6 = xp[1152], v7 = xp[1216];
      shortx8 bf;
      unsigned* bu = (unsigned*)&bf;
      bu[0] = pk2(v0, v1); bu[1] = pk2(v2, v3);
      bu[2] = pk2(v4, v5); bu[3] = pk2(v6, v7);
#pragma unroll
      for (int m = 0; m < 4; ++m) {
        int c = (cgrp * 4 + m) * 16 + nrel;
        const float* wp = Wv + (size_t)c * 512 + kt * 32 + kg * 4;
        float4 a0 = *(const float4*)wp;
        float4 a1 = *(const float4*)(wp + 16);
        shortx8 af;
        unsigned* au = (unsigned*)&af;
        au[0] = pk2(a0.x, a0.y); au[1] = pk2(a0.z, a0.w);
        au[2] = pk2(a1.x, a1.y); au[3] = pk2(a1.z, a1.w);
        acc[m] = __builtin_amdgcn_mfma_f32_16x16x32_bf16(af, bf, acc[m], 0, 0, 0);
      }
    }
#pragma unroll
    for (int m = 0; m < 4; ++m)
#pragma unroll
      for (int r = 0; r < 4; ++r) {
        int c = (cgrp * 4 + m) * 16 + kg * 4 + r;
        vmb[(size_t)(b * 512 + c) * 64 + wt * 16 + nrel] = f2bf(acc[m][r] + bv[c]);
      }
  } else {
    int idx = blk - 64;                 // 0..127
    int b = idx >> 5, og = idx & 31;
    int o = og * 8 + (t >> 4), i = t & 15;
    const float* Wr = Wk + (size_t)o * 512;
    const float* xb = x1pe + ((size_t)b * 512) * 16 + i;
    float a0 = 0.f, a1 = 0.f, a2 = 0.f, a3 = 0.f;
    for (int c = 0; c < 512; c += 4) {
      a0 += Wr[c]     * xb[c * 16];
      a1 += Wr[c + 1] * xb[(c + 1) * 16];
      a2 += Wr[c + 2] * xb[(c + 2) * 16];
      a3 += Wr[c + 3] * xb[(c + 3) * 16];
    }
    K1[((b << 8) + o) * 16 + i] = bk[o] + a0 + a1 + a2 + a3;
  }
}

// ---------------------------------------------------------------------------
// K3: m1A (bf16, A-fragment layout) = Wq^T @ K1 ; cb1[b,i] = bq . K1
// m1A element (kt, i, kg, j) = M1[c = kt*32 + kg*4 + j + (j>=4 ? 12 : 0)][i]
__global__ __launch_bounds__(256) void k_m1(const float* __restrict__ Wq,
                                            const float* __restrict__ bq,
                                            const float* __restrict__ K1,
                                            unsigned short* __restrict__ m1A,
                                            float* __restrict__ cb1) {
  int t = threadIdx.x;
  int blk = blockIdx.x;
  if (blk < 128) {
    int b = blk >> 5;
    int c = (blk & 31) * 16 + (t >> 4);
    int i = t & 15;
    const float* Wc = Wq + c;
    const float* Kb = K1 + (b << 8) * 16 + i;
    float a0 = 0.f, a1 = 0.f, a2 = 0.f, a3 = 0.f;
    for (int o = 0; o < OKD; o += 4) {
      a0 += Wc[o * CDIM]       * Kb[o * 16];
      a1 += Wc[(o + 1) * CDIM] * Kb[(o + 1) * 16];
      a2 += Wc[(o + 2) * CDIM] * Kb[(o + 2) * 16];
      a3 += Wc[(o + 3) * CDIM] * Kb[(o + 3) * 16];
    }
    float acc = a0 + a1 + a2 + a3;
    int kt = c >> 5, kl = c & 31;
    int kg = (kl < 16) ? (kl >> 2) : ((kl - 16) >> 2);
    int j  = (kl & 3) + ((kl < 16) ? 0 : 4);
    m1A[(size_t)b * 8192 + ((kt * 16 + i) * 4 + kg) * 8 + j] = f2bf(acc);
  } else if (t < 64) {
    int b = t >> 4, i = t & 15;
    const float* Kb = K1 + (b << 8) * 16 + i;
    float acc = 0.f;
    for (int o = 0; o < OKD; ++o) acc += bq[o] * Kb[o * 16];
    cb1[b * 16 + i] = acc;
  }
}

// ---------------------------------------------------------------------------
// K4: fused attention per (b, 32-n tile), 512 thr, 2 barriers.
//  Phase A (MFMA): E1^T[i][n] = (M1^T @ x_tile), 8 waves K-split 512->64
//  Phase B (regs): reduce partials, lerp i->w, softmax via shfl, pack bf16
//  Phase C (MFMA): out = gamma * (vm @ p^T) + x
__global__ __launch_bounds__(512, 4) void k_attn(const float* __restrict__ x,
                                                 const unsigned short* __restrict__ m1A,
                                                 const float* __restrict__ cb1,
                                                 const unsigned short* __restrict__ vmb,
                                                 const float* __restrict__ gamma,
                                                 float* __restrict__ out) {
  __shared__ float e1w[8][32][17];          // 17408 B
  __shared__ __align__(16) char p_t[4096];  // bf16 [32 rows][16 granules*8B], XOR-swizzled

  const int t = threadIdx.x;
  const int lane = t & 63;
  const int wv = t >> 6;            // 0..7
  const int b  = blockIdx.x >> 7;
  const int n0 = (blockIdx.x & 127) * 32;
  const int nrel = lane & 15;
  const int kg = lane >> 4;         // 0..3

  // ---- Phase A: per-wave K-slice c in [wv*64, wv*64+64) ------------------
  {
    f32x4 pacc[2] = {{0,0,0,0},{0,0,0,0}};
#pragma unroll
    for (int ktw = 0; ktw < 2; ++ktw) {
      int ktg = wv * 2 + ktw;
      shortx8 af = *(const shortx8*)(m1A + (size_t)b * 8192 +
                                     ((size_t)((ktg * 16 + nrel) * 4 + kg)) * 8);
#pragma unroll
      for (int nt = 0; nt < 2; ++nt) {
        const float* xp = x + (size_t)(b * 512 + wv * 64 + ktw * 32 + kg * 4) * NDIM +
                          n0 + nt * 16 + nrel;
        float v0 = xp[0],          v1 = xp[NDIM],        v2 = xp[2 * NDIM],  v3 = xp[3 * NDIM];
        float v4 = xp[16 * NDIM],  v5 = xp[17 * NDIM],   v6 = xp[18 * NDIM], v7 = xp[19 * NDIM];
        shortx8 bf;
        unsigned* bu = (unsigned*)&bf;
        bu[0] = pk2(v0, v1); bu[1] = pk2(v2, v3);
        bu[2] = pk2(v4, v5); bu[3] = pk2(v6, v7);
        pacc[nt] = __builtin_amdgcn_mfma_f32_16x16x32_bf16(af, bf, pacc[nt], 0, 0, 0);
      }
    }
#pragma unroll
    for (int nt = 0; nt < 2; ++nt)
#pragma unroll
      for (int r = 0; r < 4; ++r)
        e1w[wv][nt * 16 + nrel][kg * 4 + r] = pacc[nt][r];
  }
  __syncthreads();

  // ---- Phase B: reduce 8 partials, lerp to w=64, softmax, pack ------------
  {
    const int sn = t >> 4;       // n 0..31
    const int si = t & 15;       // i
    float ev = cb1[b * 16 + si];
#pragma unroll
    for (int g = 0; g < 8; ++g) ev += e1w[g][sn][si];
    float pv[4];
    float mx = -3.4e38f;
#pragma unroll
    for (int j = 0; j < 4; ++j) {
      int w = si * 4 + j;
      float srcf = (float)w * (15.0f / 63.0f);
      int i0 = (int)srcf;
      float tf = srcf - (float)i0;
      int i1 = i0 + 1; if (i1 > 15) i1 = 15;
      float v0 = __shfl(ev, (lane & 48) | i0);
      float v1 = __shfl(ev, (lane & 48) | i1);
      float vv = v0 * (1.0f - tf) + v1 * tf;
      pv[j] = vv;
      mx = fmaxf(mx, vv);
    }
    mx = fmaxf(mx, __shfl_xor(mx, 1));
    mx = fmaxf(mx, __shfl_xor(mx, 2));
    mx = fmaxf(mx, __shfl_xor(mx, 4));
    mx = fmaxf(mx, __shfl_xor(mx, 8));
    float s = 0.f;
#pragma unroll
    for (int j = 0; j < 4; ++j) { pv[j] = __expf(pv[j] - mx); s += pv[j]; }
    s += __shfl_xor(s, 1); s += __shfl_xor(s, 2);
    s += __shfl_xor(s, 4); s += __shfl_xor(s, 8);
    float inv = 1.0f / s;
    unsigned lo = pk2(pv[0] * inv, pv[1] * inv);
    unsigned hi = pk2(pv[2] * inv, pv[3] * inv);
    unsigned* dst = (unsigned*)(p_t + sn * 128 + ((si ^ (sn & 15)) << 3));
    dst[0] = lo; dst[1] = hi;
  }
  __syncthreads();

  // ---- Phase C: MFMA PV + residual ---------------------------------------
  {
    const float gm = gamma[0];
#pragma unroll
    for (int j = 0; j < 8; ++j) {
      const int idx = wv * 8 + j;
      const int ct = idx >> 1, nt = idx & 1;
      f32x4 dacc = {0.f, 0.f, 0.f, 0.f};
      const unsigned short* vrow =
          vmb + ((size_t)(b * CDIM + ct * 16 + nrel)) * 64 + kg * 4;
      const char* prow = p_t + (nt * 16 + nrel) * 128;
#pragma unroll
      for (int ks = 0; ks < 2; ++ks) {
        shortx4 a0 = *(const shortx4*)(vrow + ks * 32);
        shortx4 a1 = *(const shortx4*)(vrow + ks * 32 + 16);
        shortx8 av = __builtin_shufflevector(a0, a1, 0, 1, 2, 3, 4, 5, 6, 7);
        int G0 = (ks * 8 + kg) ^ nrel;
        int G1 = (ks * 8 + 4 + kg) ^ nrel;
        shortx4 b0 = *(const shortx4*)(prow + G0 * 8);
        shortx4 b1 = *(const shortx4*)(prow + G1 * 8);
        shortx8 bv2 = __builtin_shufflevector(b0, b1, 0, 1, 2, 3, 4, 5, 6, 7);
        dacc = __builtin_amdgcn_mfma_f32_16x16x32_bf16(av, bv2, dacc, 0, 0, 0);
      }
#pragma unroll
      for (int r = 0; r < 4; ++r) {
        int c_o = ct * 16 + kg * 4 + r;
        size_t base = (size_t)(b * CDIM + c_o) * NDIM + n0 + nt * 16 + nrel;
        out[base] = gm * dacc[r] + x[base];
      }
    }
  }
}

// ---------------------------------------------------------------------------
extern "C" void kernel_launch(void* const* d_in, const int* in_sizes, int n_in,
                              void* d_out, int out_size, void* d_ws, size_t ws_size,
                              hipStream_t stream) {
  const float* x     = (const float*)d_in[0];
  const float* Wq    = (const float*)d_in[1];
  const float* bq    = (const float*)d_in[2];
  const float* Wk    = (const float*)d_in[3];
  const float* bk    = (const float*)d_in[4];
  const float* Wv    = (const float*)d_in[5];
  const float* bv    = (const float*)d_in[6];
  const float* gamma = (const float*)d_in[7];
  const float* pe    = (const float*)d_in[8];
  const int*   pos   = (const int*)d_in[9];
  float* out = (float*)d_out;
  float* ws  = (float*)d_ws;

  float* xmh  = ws + OFF_XMH;
  float* x1pe = ws + OFF_X1;
  float* K1   = ws + OFF_K1;
  unsigned short* m1A = (unsigned short*)(ws + OFF_M1A);
  float* cb1  = ws + OFF_CB1;
  unsigned short* vmb = (unsigned short*)(ws + OFF_VMB);

  hipLaunchKernelGGL(k_reduce, dim3(512), dim3(256), 0, stream, x, pe, pos, xmh, x1pe);
  hipLaunchKernelGGL(k_vmk1, dim3(192), dim3(128), 0, stream, Wv, bv, Wk, bk, xmh, x1pe, vmb, K1);
  hipLaunchKernelGGL(k_m1, dim3(129), dim3(256), 0, stream, Wq, bq, K1, m1A, cb1);
  hipLaunchKernelGGL(k_attn, dim3(512), dim3(512), 0, stream, x, m1A, cb1, vmb, gamma, out);
}